// Round 1
// baseline (488.089 us; speedup 1.0000x reference)
//
#include <hip/hip_runtime.h>
#include <hip/hip_bf16.h>

#define NN 50000
#define NE 800000

typedef __attribute__((ext_vector_type(8))) short short8;
typedef __attribute__((ext_vector_type(4))) float f32x4;

static __device__ __forceinline__ short f2bf(float f) {
    __hip_bfloat16 h = __float2bfloat16(f);   // RNE
    return __builtin_bit_cast(short, h);
}

static __device__ __forceinline__ short8 cvt8(f32x4 a, f32x4 b) {
    short8 v;
    v[0] = f2bf(a[0]); v[1] = f2bf(a[1]); v[2] = f2bf(a[2]); v[3] = f2bf(a[3]);
    v[4] = f2bf(b[0]); v[5] = f2bf(b[1]); v[6] = f2bf(b[2]); v[7] = f2bf(b[3]);
    return v;
}

// Load B fragments for a [K][64] fp32 weight matrix into per-lane registers.
// Slot map: frag[t][nt][i] = W[(32t + 8g + i)][16nt + er]  (consistent A/B bijection)
#define LOAD_BFRAGS(W, FR, KT)                                        \
    _Pragma("unroll")                                                 \
    for (int t = 0; t < (KT); ++t) {                                  \
        _Pragma("unroll")                                             \
        for (int nt = 0; nt < 4; ++nt) {                              \
            short8 v;                                                 \
            _Pragma("unroll")                                         \
            for (int i = 0; i < 8; ++i)                               \
                v[i] = f2bf((W)[(32*t + 8*g + i)*64 + 16*nt + er]);   \
            FR[t][nt] = v;                                            \
        }                                                             \
    }

__global__ __launch_bounds__(256, 2) void edge_kernel(
    const float* __restrict__ x, const int* __restrict__ ei,
    const float* __restrict__ ea,
    const float* __restrict__ W1a, const float* __restrict__ b1a,
    const float* __restrict__ W1b, const float* __restrict__ b1b,
    float* __restrict__ summed, float* __restrict__ counts)
{
    __shared__ short h1s[4][16*64];          // per-wave transpose buffer (XOR-swizzled)
    const int tid  = threadIdx.x;
    const int wid  = tid >> 6;
    const int lane = tid & 63;
    const int er   = lane & 15;              // edge-in-tile (A row / C col index)
    const int g    = lane >> 4;
    short* myh1 = h1s[wid];

    short8 Wa[4][4];                         // layer1 weights, K=128
    short8 Wb[2][4];                         // layer2 weights, K=64
    LOAD_BFRAGS(W1a, Wa, 4)
    LOAD_BFRAGS(W1b, Wb, 2)
    float bias1[4], bias2[4];
    #pragma unroll
    for (int nt = 0; nt < 4; ++nt) { bias1[nt] = b1a[16*nt + er]; bias2[nt] = b1b[16*nt + er]; }

    for (int tile = blockIdx.x * 4 + wid; tile < NE/16; tile += gridDim.x * 4) {
        const int eb  = tile * 16;
        const int col = ei[NE + eb + er];                 // gather index (edge target)
        const float* xr = x  + (size_t)col * 64;
        const float* qr = ea + (size_t)(eb + er) * 64;

        // A fragments: in[e] = [x[col[e]] | ea[e]], k = 32t + 8g + i
        short8 A[4];
        #pragma unroll
        for (int t = 0; t < 2; ++t) {
            f32x4 v0 = *(const f32x4*)(xr + 32*t + 8*g);
            f32x4 v1 = *(const f32x4*)(xr + 32*t + 8*g + 4);
            A[t] = cvt8(v0, v1);
        }
        #pragma unroll
        for (int t = 0; t < 2; ++t) {
            f32x4 v0 = *(const f32x4*)(qr + 32*t + 8*g);
            f32x4 v1 = *(const f32x4*)(qr + 32*t + 8*g + 4);
            A[2+t] = cvt8(v0, v1);
        }

        f32x4 acc[4] = {{0,0,0,0},{0,0,0,0},{0,0,0,0},{0,0,0,0}};
        #pragma unroll
        for (int t = 0; t < 4; ++t)
            #pragma unroll
            for (int nt = 0; nt < 4; ++nt)
                acc[nt] = __builtin_amdgcn_mfma_f32_16x16x32_bf16(A[t], Wa[t][nt], acc[nt], 0, 0, 0);

        // h1 = relu(acc + b1a); write transposed (edge-major) into LDS, XOR swizzle
        #pragma unroll
        for (int r = 0; r < 4; ++r) {
            const int e = 4*g + r;                        // C row = edge-in-tile
            const int swz = (e & 7) << 3;
            #pragma unroll
            for (int nt = 0; nt < 4; ++nt) {
                float h = acc[nt][r] + bias1[nt];
                h = h > 0.0f ? h : 0.0f;
                myh1[e*64 + ((16*nt + er) ^ swz)] = f2bf(h);
            }
        }

        // layer 2: A2[e][k2], k2 = 32t + 8g + i, read back swizzled
        const int swr = (er & 7) << 3;
        short8 A2[2];
        #pragma unroll
        for (int t = 0; t < 2; ++t)
            A2[t] = *(const short8*)(myh1 + er*64 + ((32*t + 8*g) ^ swr));

        f32x4 acc2[4] = {{0,0,0,0},{0,0,0,0},{0,0,0,0},{0,0,0,0}};
        #pragma unroll
        for (int t = 0; t < 2; ++t)
            #pragma unroll
            for (int nt = 0; nt < 4; ++nt)
                acc2[nt] = __builtin_amdgcn_mfma_f32_16x16x32_bf16(A2[t], Wb[t][nt], acc2[nt], 0, 0, 0);

        // scatter-add msg into summed[row[e]]
        #pragma unroll
        for (int r = 0; r < 4; ++r) {
            const int rid = ei[eb + 4*g + r];
            float* dst = summed + (size_t)rid * 64 + er;
            #pragma unroll
            for (int nt = 0; nt < 4; ++nt)
                atomicAdd(dst + 16*nt, acc2[nt][r] + bias2[nt]);
        }
        if (g == 0)
            atomicAdd(counts + ei[eb + er], 1.0f);
    }
}

__global__ __launch_bounds__(256, 2) void node_kernel(
    const float* __restrict__ x, const float* __restrict__ counts,
    const float* __restrict__ W2a, const float* __restrict__ b2a,
    const float* __restrict__ W2b, const float* __restrict__ b2b,
    float* out /* doubles as summed (in) and final output */)
{
    __shared__ short h1s[4][16*64];
    const int tid  = threadIdx.x;
    const int wid  = tid >> 6;
    const int lane = tid & 63;
    const int er   = lane & 15;
    const int g    = lane >> 4;
    short* myh1 = h1s[wid];

    short8 Wa[4][4];
    short8 Wb[2][4];
    LOAD_BFRAGS(W2a, Wa, 4)
    LOAD_BFRAGS(W2b, Wb, 2)
    float bias1[4], bias2[4];
    #pragma unroll
    for (int nt = 0; nt < 4; ++nt) { bias1[nt] = b2a[16*nt + er]; bias2[nt] = b2b[16*nt + er]; }

    const int tile = blockIdx.x * 4 + wid;
    if (tile >= NN/16) return;
    const int nb   = tile * 16;
    const int node = nb + er;

    const float* xr = x   + (size_t)node * 64;
    const float* sr = out + (size_t)node * 64;            // summed row
    const float  c  = counts[node];
    const float  rc = 1.0f / fmaxf(c, 1.0f);

    short8 A[4];
    #pragma unroll
    for (int t = 0; t < 2; ++t) {
        f32x4 v0 = *(const f32x4*)(xr + 32*t + 8*g);
        f32x4 v1 = *(const f32x4*)(xr + 32*t + 8*g + 4);
        A[t] = cvt8(v0, v1);
    }
    #pragma unroll
    for (int t = 0; t < 2; ++t) {
        f32x4 v0 = *(const f32x4*)(sr + 32*t + 8*g);
        f32x4 v1 = *(const f32x4*)(sr + 32*t + 8*g + 4);
        v0 *= rc; v1 *= rc;                               // agg = summed / max(count,1)
        A[2+t] = cvt8(v0, v1);
    }

    f32x4 acc[4] = {{0,0,0,0},{0,0,0,0},{0,0,0,0},{0,0,0,0}};
    #pragma unroll
    for (int t = 0; t < 4; ++t)
        #pragma unroll
        for (int nt = 0; nt < 4; ++nt)
            acc[nt] = __builtin_amdgcn_mfma_f32_16x16x32_bf16(A[t], Wa[t][nt], acc[nt], 0, 0, 0);

    #pragma unroll
    for (int r = 0; r < 4; ++r) {
        const int e = 4*g + r;
        const int swz = (e & 7) << 3;
        #pragma unroll
        for (int nt = 0; nt < 4; ++nt) {
            float h = acc[nt][r] + bias1[nt];
            h = h > 0.0f ? h : 0.0f;
            myh1[e*64 + ((16*nt + er) ^ swz)] = f2bf(h);
        }
    }

    const int swr = (er & 7) << 3;
    short8 A2[2];
    #pragma unroll
    for (int t = 0; t < 2; ++t)
        A2[t] = *(const short8*)(myh1 + er*64 + ((32*t + 8*g) ^ swr));

    f32x4 acc2[4] = {{0,0,0,0},{0,0,0,0},{0,0,0,0},{0,0,0,0}};
    #pragma unroll
    for (int t = 0; t < 2; ++t)
        #pragma unroll
        for (int nt = 0; nt < 4; ++nt)
            acc2[nt] = __builtin_amdgcn_mfma_f32_16x16x32_bf16(A2[t], Wb[t][nt], acc2[nt], 0, 0, 0);

    #pragma unroll
    for (int r = 0; r < 4; ++r) {
        float* orow = out + (size_t)(nb + 4*g + r) * 64 + er;
        #pragma unroll
        for (int nt = 0; nt < 4; ++nt)
            orow[16*nt] = acc2[nt][r] + bias2[nt];
    }
}

extern "C" void kernel_launch(void* const* d_in, const int* in_sizes, int n_in,
                              void* d_out, int out_size, void* d_ws, size_t ws_size,
                              hipStream_t stream)
{
    const float* x   = (const float*)d_in[0];
    const int*   ei  = (const int*)d_in[1];
    const float* ea  = (const float*)d_in[2];
    // d_in[3] = u (unused), d_in[4] = batch (unused)
    const float* W1a = (const float*)d_in[5];
    const float* b1a = (const float*)d_in[6];
    const float* W1b = (const float*)d_in[7];
    const float* b1b = (const float*)d_in[8];
    const float* W2a = (const float*)d_in[9];
    const float* b2a = (const float*)d_in[10];
    const float* W2b = (const float*)d_in[11];
    const float* b2b = (const float*)d_in[12];

    float* out    = (float*)d_out;      // reused as the scatter-sum accumulator
    float* counts = (float*)d_ws;       // 50000 floats

    hipMemsetAsync(out,    0, (size_t)NN * 64 * sizeof(float), stream);
    hipMemsetAsync(counts, 0, (size_t)NN * sizeof(float),      stream);

    // 50000 edge tiles of 16; 3125 blocks x 4 waves, 4 tiles per wave (grid-stride)
    edge_kernel<<<3125, 256, 0, stream>>>(x, ei, ea, W1a, b1a, W1b, b1b, out, counts);
    // 3125 node tiles of 16; 1 tile per wave
    node_kernel<<<782, 256, 0, stream>>>(x, counts, W2a, b2a, W2b, b2b, out);
}